// Round 13
// baseline (228.789 us; speedup 1.0000x reference)
//
#include <hip/hip_runtime.h>
#include <math.h>

#define NB 16
#define NCH 128
#define NH 64
#define NW 64
#define NP 1024

#define TN 32    // rows per tile
#define TM 128   // cols per tile
#define KC 32    // k chunk
#define KP 36    // padded k stride in LDS (zero-conflict at this codegen, verified R1/R11/R12)

#define NTILE 144  // symmetric tile count: sum_{g=0..7} 4*(8-g)

__device__ __forceinline__ float med3(float a, float b, float c) {
  return __builtin_amdgcn_fmed3f(a, b, c);
}

__device__ __forceinline__ void top3_ins(float& t0, float& t1, float& t2, float a) {
  float n0 = fmaxf(t0, a);
  float n1 = med3(a, t0, t1);
  float n2 = med3(a, t1, t2);
  t0 = n0; t1 = n1; t2 = n2;
}

__device__ __forceinline__ float dot4(float4 a, float4 b) {
  return a.x * b.x + a.y * b.y + a.z * b.z + a.w * b.w;
}

// ---------------- zero: init row-sum accumulators (ws is 0xAA-poisoned) ----------------
__global__ __launch_bounds__(256) void zero_kernel(float* __restrict__ p, int nelem) {
  int i = blockIdx.x * 256 + threadIdx.x;
  if (i < nelem) p[i] = 0.f;
}

// ---------------- prep ----------------
__global__ __launch_bounds__(256) void prep_kernel(const float* __restrict__ x,
                                                   float* __restrict__ V) {
  int blk = blockIdx.x;
  int t = threadIdx.x;
  int b = blk >> 3;
  int c = (blk >> 2) & 1;
  int n = (blk & 3) * 256 + t;
  int i = 2 * (n >> 5) + c;
  int j = 2 * (n & 31) + c;
  const float* xp = x + (size_t)b * NCH * NH * NW + i * NW + j;
  float ss = 0.f;
#pragma unroll 8
  for (int ch = 0; ch < NCH; ++ch) {
    float v = xp[(size_t)ch * NH * NW];
    ss += v * v;
  }
  float r = 1.0f / fmaxf(sqrtf(ss), 1e-12f);
  float* vp = V + (((size_t)b * 2 + c) * NP + n) * NCH;
#pragma unroll 8
  for (int ch = 0; ch < NCH; ++ch) {
    vp[ch] = xp[(size_t)ch * NH * NW] * r;
  }
}

// ================= FAST PATH =================
// Symmetric GEMM (144 of 256 tiles) + fused exp-row-sum accumulation.
// Each Sbuf entry (r,c) is written exactly once (direct iff c>=r, mirror iff r>c),
// so accumulating exp() over exactly the entries each block WRITES gives exact
// row sums with no double counting.
__global__ __launch_bounds__(256, 2) void gemm_sym(
    const float* __restrict__ V, const float* __restrict__ alpha_p,
    float2* __restrict__ Sbuf, float* __restrict__ rsum) {
  // LDS union: staging (As|Bs = 46080 B) then transpose buffer Ts (33792 B)
  __shared__ __align__(16) char smem_raw[2 * TN * KP * 4 + 2 * TM * KP * 4];
  float (*As)[TN][KP] = reinterpret_cast<float (*)[TN][KP]>(smem_raw);
  float (*Bs)[TM][KP] = reinterpret_cast<float (*)[TM][KP]>(smem_raw + 2 * TN * KP * 4);
  float2 (*Ts)[TN + 1] = reinterpret_cast<float2 (*)[TN + 1]>(smem_raw);

  const int b = blockIdx.y;
  // map blockIdx.x -> (ni, mj): groups g = ni>>2 have 4*(8-g) tiles each
  int id = blockIdx.x;
  int g = 0;
  while (id >= 4 * (8 - g)) { id -= 4 * (8 - g); ++g; }
  const int ni = 4 * g + id / (8 - g);
  const int mj = g + id % (8 - g);
  const int n0 = ni * TN;
  const int m0 = mj * TM;

  const int t = threadIdx.x;
  const int tx = t & 31;   // m-slot: m = m0 + tx + 32*j
  const int ty = t >> 5;   // row group: rows n0 + ty*4 + i
  const float alpha = *alpha_p;
  const float* Vb = V + (size_t)b * 2 * NP * NCH;
  float* rs = rsum + (size_t)b * 3 * NP;

  float acc[2][4][4];
#pragma unroll
  for (int c = 0; c < 2; ++c)
#pragma unroll
    for (int i = 0; i < 4; ++i)
#pragma unroll
      for (int j = 0; j < 4; ++j) acc[c][i][j] = 0.f;

  for (int k0 = 0; k0 < NCH; k0 += KC) {
    __syncthreads();
    // stage A tile: 2*32*32 floats = 512 float4 -> 2 per thread
#pragma unroll
    for (int q = 0; q < 2; ++q) {
      int flat = q * 256 + t;
      int c = flat >> 8;
      int rem = flat & 255;
      int row = rem >> 3;
      int kg = rem & 7;
      float4 v4 = *(const float4*)(Vb + ((size_t)c * NP + n0 + row) * NCH + k0 + kg * 4);
      *(float4*)&As[c][row][kg * 4] = v4;
    }
    // stage B tile: 2*128*32 floats = 2048 float4 -> 8 per thread
#pragma unroll
    for (int q = 0; q < 8; ++q) {
      int flat = q * 256 + t;
      int c = flat >> 10;
      int rem = flat & 1023;
      int row = rem >> 3;
      int kg = rem & 7;
      float4 v4 = *(const float4*)(Vb + ((size_t)c * NP + m0 + row) * NCH + k0 + kg * 4);
      *(float4*)&Bs[c][row][kg * 4] = v4;
    }
    __syncthreads();

    for (int kg = 0; kg < KC; kg += 4) {
      float4 a4[2][4], b4[2][4];
#pragma unroll
      for (int c = 0; c < 2; ++c)
#pragma unroll
        for (int i = 0; i < 4; ++i)
          a4[c][i] = *(const float4*)&As[c][ty * 4 + i][kg];
#pragma unroll
      for (int c = 0; c < 2; ++c)
#pragma unroll
        for (int j = 0; j < 4; ++j)
          b4[c][j] = *(const float4*)&Bs[c][tx + 32 * j][kg];
#pragma unroll
      for (int c = 0; c < 2; ++c)
#pragma unroll
        for (int i = 0; i < 4; ++i)
#pragma unroll
          for (int j = 0; j < 4; ++j)
            acc[c][i][j] += dot4(a4[c][i], b4[c][j]);
    }
  }

  // ---- epilogue ----
  __syncthreads();  // staging reads done; smem may be reused as Ts
  float sm[3][4];
#pragma unroll
  for (int c = 0; c < 3; ++c)
#pragma unroll
    for (int i = 0; i < 4; ++i) sm[c][i] = 0.f;

#pragma unroll
  for (int i = 0; i < 4; ++i) {
    int n = n0 + ty * 4 + i;
    int nr = n >> 5, nc = n & 31;
    float2* rowp = Sbuf + ((size_t)b * NP + n) * NP;
#pragma unroll
    for (int j = 0; j < 4; ++j) {
      int m = m0 + tx + 32 * j;
      int dr = nr - (m >> 5);
      int dc = nc - (m & 31);
      float gss = __expf(-(float)(dr * dr + dc * dc) * 0.1953125f);  // 1/5.12 exact
      float wgt = (1.0f - gss) * alpha;
      float2 sv = make_float2(acc[0][i][j] * wgt, acc[1][i][j] * wgt);
      Ts[tx + 32 * j][ty * 4 + i] = sv;  // stage for mirror
      if (m >= n) {                      // direct (upper incl. diagonal)
        rowp[m] = sv;
        sm[0][i] += __expf(sv.x);
        sm[1][i] += __expf(sv.y);
        sm[2][i] += __expf(0.5f * (sv.x + sv.y));
      }
    }
  }
  // direct row-partials: reduce over 32 tx lanes, atomic per (c, row)
#pragma unroll
  for (int off = 1; off < 32; off <<= 1) {
#pragma unroll
    for (int c = 0; c < 3; ++c)
#pragma unroll
      for (int i = 0; i < 4; ++i)
        sm[c][i] += __shfl_xor(sm[c][i], off, 64);
  }
  if (tx == 0) {
#pragma unroll
    for (int c = 0; c < 3; ++c)
#pragma unroll
      for (int i = 0; i < 4; ++i)
        atomicAdd(&rs[(size_t)c * NP + (n0 + ty * 4 + i)], sm[c][i]);
  }

  __syncthreads();
  // mirror write + mirror row-partials (rows m of the transposed entries)
#pragma unroll
  for (int q = 0; q < 16; ++q) {
    int flat = q * 256 + t;
    int ml = flat >> 5;
    int r = flat & 31;
    int m = m0 + ml;
    int n = n0 + r;
    float2 sv = Ts[ml][r];
    bool wr = (m > n);
    if (wr) Sbuf[((size_t)b * NP + m) * NP + n] = sv;
    float e0 = wr ? __expf(sv.x) : 0.f;
    float e1 = wr ? __expf(sv.y) : 0.f;
    float e2 = wr ? __expf(0.5f * (sv.x + sv.y)) : 0.f;
    // sum over the 32 r-lanes (xor offs < 32 stay within each 32-lane half)
#pragma unroll
    for (int off = 1; off < 32; off <<= 1) {
      e0 += __shfl_xor(e0, off, 64);
      e1 += __shfl_xor(e1, off, 64);
      e2 += __shfl_xor(e2, off, 64);
    }
    if ((t & 31) == 0) {
      atomicAdd(&rs[(size_t)0 * NP + m], e0);
      atomicAdd(&rs[(size_t)1 * NP + m], e1);
      atomicAdd(&rs[(size_t)2 * NP + m], e2);
    }
  }
}

// reciprocal in-place: rinv[i] = 1/rsum[i]
__global__ __launch_bounds__(256) void recip_kernel(float* __restrict__ p, int nelem) {
  int i = blockIdx.x * 256 + threadIdx.x;
  if (i < nelem) p[i] = 1.0f / p[i];
}

// topk: one block per (b, n-row): A=exp(2s)*rinv_n*rinv_m, top-3, scatter.
__global__ __launch_bounds__(256, 4) void topk_kernel(
    const float2* __restrict__ Sbuf, const float* __restrict__ rinv,
    float* __restrict__ out) {
  const int n = blockIdx.x, b = blockIdx.y;
  const int t = threadIdx.x;
  const float* rb = rinv + (size_t)b * 3 * NP;
  float rin[3];
#pragma unroll
  for (int c = 0; c < 3; ++c) rin[c] = rb[c * NP + n];
  const float2* row = Sbuf + ((size_t)b * NP + n) * NP;

  float t0[3] = {0.f, 0.f, 0.f}, t1[3] = {0.f, 0.f, 0.f}, t2[3] = {0.f, 0.f, 0.f};
#pragma unroll
  for (int q = 0; q < 4; ++q) {
    int m = t + q * 256;
    float2 s01 = row[m];
    float s[3];
    s[0] = s01.x; s[1] = s01.y; s[2] = 0.5f * (s01.x + s01.y);
#pragma unroll
    for (int c = 0; c < 3; ++c) {
      float a = __expf(2.0f * s[c]) * rin[c] * rb[c * NP + m];
      top3_ins(t0[c], t1[c], t2[c], a);
    }
  }
#pragma unroll
  for (int off = 1; off < 64; off <<= 1) {
#pragma unroll
    for (int c = 0; c < 3; ++c) {
      float o0 = __shfl_xor(t0[c], off, 64);
      float o1 = __shfl_xor(t1[c], off, 64);
      float o2 = __shfl_xor(t2[c], off, 64);
      top3_ins(t0[c], t1[c], t2[c], o0);
      top3_ins(t0[c], t1[c], t2[c], o1);
      top3_ins(t0[c], t1[c], t2[c], o2);
    }
  }
  __shared__ float lds[4][9];
  if ((t & 63) == 0) {
    int w = t >> 6;
#pragma unroll
    for (int c = 0; c < 3; ++c) {
      lds[w][c * 3 + 0] = t0[c];
      lds[w][c * 3 + 1] = t1[c];
      lds[w][c * 3 + 2] = t2[c];
    }
  }
  __syncthreads();
  if (t == 0) {
#pragma unroll
    for (int w = 1; w < 4; ++w)
#pragma unroll
      for (int c = 0; c < 3; ++c) {
        top3_ins(t0[c], t1[c], t2[c], lds[w][c * 3 + 0]);
        top3_ins(t0[c], t1[c], t2[c], lds[w][c * 3 + 1]);
        top3_ins(t0[c], t1[c], t2[c], lds[w][c * 3 + 2]);
      }
    int pr = n >> 5, pc = n & 31;
#pragma unroll
    for (int c = 0; c < 3; ++c) {
      int ii0, jj0, ii1 = -1, jj1 = -1;
      if (c == 0)      { ii0 = 2 * pr;     jj0 = 2 * pc; }
      else if (c == 1) { ii0 = 2 * pr + 1; jj0 = 2 * pc + 1; }
      else             { ii0 = 2 * pr;     jj0 = 2 * pc + 1;
                         ii1 = 2 * pr + 1; jj1 = 2 * pc; }
      out[(((size_t)b * 3 + 0) * NH + ii0) * NW + jj0] = t0[c];
      out[(((size_t)b * 3 + 1) * NH + ii0) * NW + jj0] = t1[c];
      out[(((size_t)b * 3 + 2) * NH + ii0) * NW + jj0] = t2[c];
      if (ii1 >= 0) {
        out[(((size_t)b * 3 + 0) * NH + ii1) * NW + jj1] = t0[c];
        out[(((size_t)b * 3 + 1) * NH + ii1) * NW + jj1] = t1[c];
        out[(((size_t)b * 3 + 2) * NH + ii1) * NW + jj1] = t2[c];
      }
    }
  }
}

// ================= FALLBACK PATH (round-1 kernels, verified) =================
template <int PASS>
__global__ __launch_bounds__(256, 2) void corr_kernel(
    const float* __restrict__ V, const float* __restrict__ alpha_p,
    float* __restrict__ rsum_g, float* __restrict__ out) {
  __shared__ __align__(16) float As[2][TN][KP];
  __shared__ __align__(16) float Bs[2][TM][KP];

  const int b = blockIdx.y;
  const int n0 = blockIdx.x * TN;
  const int t = threadIdx.x;
  const int tx = t & 31;
  const int ty = t >> 5;
  const float alpha = *alpha_p;
  const float* Vb = V + (size_t)b * 2 * NP * NCH;

  float sm[3][4];
  float t0[3][4], t1[3][4], t2[3][4];
  float rin[3][4];
#pragma unroll
  for (int c = 0; c < 3; ++c)
#pragma unroll
    for (int i = 0; i < 4; ++i) {
      sm[c][i] = 0.f;
      t0[c][i] = 0.f; t1[c][i] = 0.f; t2[c][i] = 0.f;
    }
  if (PASS == 2) {
#pragma unroll
    for (int c = 0; c < 3; ++c)
#pragma unroll
      for (int i = 0; i < 4; ++i) {
        int n = n0 + ty * 4 + i;
        rin[c][i] = 1.0f / rsum_g[((size_t)b * 3 + c) * NP + n];
      }
  }

  for (int mc = 0; mc < NP / TM; ++mc) {
    const int m0 = mc * TM;
    float acc[2][4][4];
#pragma unroll
    for (int c = 0; c < 2; ++c)
#pragma unroll
      for (int i = 0; i < 4; ++i)
#pragma unroll
        for (int j = 0; j < 4; ++j) acc[c][i][j] = 0.f;

    for (int k0 = 0; k0 < NCH; k0 += KC) {
      __syncthreads();
#pragma unroll
      for (int q = 0; q < 2; ++q) {
        int flat = q * 256 + t;
        int c = flat >> 8;
        int rem = flat & 255;
        int row = rem >> 3;
        int kg = rem & 7;
        float4 v4 = *(const float4*)(Vb + ((size_t)c * NP + n0 + row) * NCH + k0 + kg * 4);
        *(float4*)&As[c][row][kg * 4] = v4;
      }
#pragma unroll
      for (int q = 0; q < 8; ++q) {
        int flat = q * 256 + t;
        int c = flat >> 10;
        int rem = flat & 1023;
        int row = rem >> 3;
        int kg = rem & 7;
        float4 v4 = *(const float4*)(Vb + ((size_t)c * NP + m0 + row) * NCH + k0 + kg * 4);
        *(float4*)&Bs[c][row][kg * 4] = v4;
      }
      __syncthreads();

      for (int kg = 0; kg < KC; kg += 4) {
        float4 a4[2][4], b4[2][4];
#pragma unroll
        for (int c = 0; c < 2; ++c)
#pragma unroll
          for (int i = 0; i < 4; ++i)
            a4[c][i] = *(const float4*)&As[c][ty * 4 + i][kg];
#pragma unroll
        for (int c = 0; c < 2; ++c)
#pragma unroll
          for (int j = 0; j < 4; ++j)
            b4[c][j] = *(const float4*)&Bs[c][tx + 32 * j][kg];
#pragma unroll
        for (int c = 0; c < 2; ++c)
#pragma unroll
          for (int i = 0; i < 4; ++i)
#pragma unroll
            for (int j = 0; j < 4; ++j)
              acc[c][i][j] += dot4(a4[c][i], b4[c][j]);
      }
    }

    float rim[3][4];
    if (PASS == 2) {
#pragma unroll
      for (int c = 0; c < 3; ++c)
#pragma unroll
        for (int j = 0; j < 4; ++j) {
          int m = m0 + tx + 32 * j;
          rim[c][j] = 1.0f / rsum_g[((size_t)b * 3 + c) * NP + m];
        }
    }
#pragma unroll
    for (int i = 0; i < 4; ++i) {
      int n = n0 + ty * 4 + i;
      int nr = n >> 5, nc = n & 31;
      float s[3][4];
#pragma unroll
      for (int j = 0; j < 4; ++j) {
        int m = m0 + tx + 32 * j;
        int dr = nr - (m >> 5);
        int dc = nc - (m & 31);
        float g = __expf(-(float)(dr * dr + dc * dc) * 0.1953125f);
        float wgt = (1.0f - g) * alpha;
        float s0v = acc[0][i][j] * wgt;
        float s1v = acc[1][i][j] * wgt;
        s[0][j] = s0v; s[1][j] = s1v; s[2][j] = 0.5f * (s0v + s1v);
      }
      if (PASS == 1) {
#pragma unroll
        for (int c = 0; c < 3; ++c) {
          sm[c][i] += __expf(s[c][0]) + __expf(s[c][1]) +
                      __expf(s[c][2]) + __expf(s[c][3]);
        }
      } else {
#pragma unroll
        for (int c = 0; c < 3; ++c) {
#pragma unroll
          for (int j = 0; j < 4; ++j) {
            float a = __expf(2.0f * s[c][j]) * rin[c][i] * rim[c][j];
            top3_ins(t0[c][i], t1[c][i], t2[c][i], a);
          }
        }
      }
    }
  }

  if (PASS == 1) {
#pragma unroll
    for (int off = 1; off < 32; off <<= 1) {
#pragma unroll
      for (int c = 0; c < 3; ++c)
#pragma unroll
        for (int i = 0; i < 4; ++i)
          sm[c][i] += __shfl_xor(sm[c][i], off, 64);
    }
    if (tx == 0) {
#pragma unroll
      for (int c = 0; c < 3; ++c)
#pragma unroll
        for (int i = 0; i < 4; ++i) {
          int n = n0 + ty * 4 + i;
          rsum_g[((size_t)b * 3 + c) * NP + n] = sm[c][i];
        }
    }
  } else {
#pragma unroll
    for (int off = 1; off < 32; off <<= 1) {
#pragma unroll
      for (int c = 0; c < 3; ++c)
#pragma unroll
        for (int i = 0; i < 4; ++i) {
          float o0 = __shfl_xor(t0[c][i], off, 64);
          float o1 = __shfl_xor(t1[c][i], off, 64);
          float o2 = __shfl_xor(t2[c][i], off, 64);
          top3_ins(t0[c][i], t1[c][i], t2[c][i], o0);
          top3_ins(t0[c][i], t1[c][i], t2[c][i], o1);
          top3_ins(t0[c][i], t1[c][i], t2[c][i], o2);
        }
    }
    if (tx == 0) {
#pragma unroll
      for (int c = 0; c < 3; ++c)
#pragma unroll
        for (int i = 0; i < 4; ++i) {
          int n = n0 + ty * 4 + i;
          int pr = n >> 5, pc = n & 31;
          float v0 = t0[c][i], v1 = t1[c][i], v2 = t2[c][i];
          int ii0, jj0, ii1 = -1, jj1 = -1;
          if (c == 0)      { ii0 = 2 * pr;     jj0 = 2 * pc; }
          else if (c == 1) { ii0 = 2 * pr + 1; jj0 = 2 * pc + 1; }
          else             { ii0 = 2 * pr;     jj0 = 2 * pc + 1;
                             ii1 = 2 * pr + 1; jj1 = 2 * pc; }
          out[(((size_t)b * 3 + 0) * NH + ii0) * NW + jj0] = v0;
          out[(((size_t)b * 3 + 1) * NH + ii0) * NW + jj0] = v1;
          out[(((size_t)b * 3 + 2) * NH + ii0) * NW + jj0] = v2;
          if (ii1 >= 0) {
            out[(((size_t)b * 3 + 0) * NH + ii1) * NW + jj1] = v0;
            out[(((size_t)b * 3 + 1) * NH + ii1) * NW + jj1] = v1;
            out[(((size_t)b * 3 + 2) * NH + ii1) * NW + jj1] = v2;
          }
        }
    }
  }
}

extern "C" void kernel_launch(void* const* d_in, const int* in_sizes, int n_in,
                              void* d_out, int out_size, void* d_ws, size_t ws_size,
                              hipStream_t stream) {
  const float* x = (const float*)d_in[0];
  const float* alpha = (const float*)d_in[1];
  float* out = (float*)d_out;

  // workspace layout (floats)
  const size_t nV = (size_t)NB * 2 * NP * NCH;      // 4,194,304
  const size_t nRs = (size_t)NB * 3 * NP;           // 49,152 (rsum -> rinv; fallback rsum)
  const size_t nS = (size_t)NB * NP * NP;           // 16,777,216 float2 slots

  float* V = (float*)d_ws;
  float* rsum = V + nV;
  float2* Sbuf = (float2*)(rsum + nRs);

  const size_t need_bytes = (nV + nRs) * 4 + nS * 8;

  if (ws_size >= need_bytes) {
    zero_kernel<<<(NB * 3 * NP + 255) / 256, 256, 0, stream>>>(rsum, NB * 3 * NP);
    prep_kernel<<<128, 256, 0, stream>>>(x, V);
    gemm_sym<<<dim3(NTILE, NB), 256, 0, stream>>>(V, alpha, Sbuf, rsum);
    recip_kernel<<<(NB * 3 * NP + 255) / 256, 256, 0, stream>>>(rsum, NB * 3 * NP);
    topk_kernel<<<dim3(NP, NB), 256, 0, stream>>>(Sbuf, rsum, out);
  } else {
    prep_kernel<<<128, 256, 0, stream>>>(x, V);
    corr_kernel<1><<<dim3(NP / TN, NB), 256, 0, stream>>>(V, alpha, rsum, out);
    corr_kernel<2><<<dim3(NP / TN, NB), 256, 0, stream>>>(V, alpha, rsum, out);
  }
}

// Round 14
// 200.995 us; speedup vs baseline: 1.1383x; 1.1383x over previous
//
#include <hip/hip_runtime.h>
#include <math.h>

#define NB 16
#define NCH 128
#define NH 64
#define NW 64
#define NP 1024

#define TN 32    // rows per tile
#define TM 128   // cols per tile
#define KC 32    // k chunk
#define KP 36    // padded k stride in LDS (zero-conflict at this codegen, verified R1/R11/R12)

#define NTILE 144  // symmetric tile count: sum_{g=0..7} 4*(8-g)

__device__ __forceinline__ float med3(float a, float b, float c) {
  return __builtin_amdgcn_fmed3f(a, b, c);
}

__device__ __forceinline__ void top3_ins(float& t0, float& t1, float& t2, float a) {
  float n0 = fmaxf(t0, a);
  float n1 = med3(a, t0, t1);
  float n2 = med3(a, t1, t2);
  t0 = n0; t1 = n1; t2 = n2;
}

__device__ __forceinline__ float dot4(float4 a, float4 b) {
  return a.x * b.x + a.y * b.y + a.z * b.z + a.w * b.w;
}

// ---------------- zero: init row-sum accumulators (ws is 0xAA-poisoned) ----------------
__global__ __launch_bounds__(256) void zero_kernel(float* __restrict__ p, int nelem) {
  int i = blockIdx.x * 256 + threadIdx.x;
  if (i < nelem) p[i] = 0.f;
}

// ---------------- prep ----------------
__global__ __launch_bounds__(256) void prep_kernel(const float* __restrict__ x,
                                                   float* __restrict__ V) {
  int blk = blockIdx.x;
  int t = threadIdx.x;
  int b = blk >> 3;
  int c = (blk >> 2) & 1;
  int n = (blk & 3) * 256 + t;
  int i = 2 * (n >> 5) + c;
  int j = 2 * (n & 31) + c;
  const float* xp = x + (size_t)b * NCH * NH * NW + i * NW + j;
  float ss = 0.f;
#pragma unroll 8
  for (int ch = 0; ch < NCH; ++ch) {
    float v = xp[(size_t)ch * NH * NW];
    ss += v * v;
  }
  float r = 1.0f / fmaxf(sqrtf(ss), 1e-12f);
  float* vp = V + (((size_t)b * 2 + c) * NP + n) * NCH;
#pragma unroll 8
  for (int ch = 0; ch < NCH; ++ch) {
    vp[ch] = xp[(size_t)ch * NH * NW] * r;
  }
}

// ================= FAST PATH =================
// Symmetric GEMM (144 of 256 tiles) + fused exp-row-sum accumulation.
// Each Sbuf entry (r,c) is written exactly once (direct iff c>=r, mirror iff r>c),
// so accumulating exp() over exactly the entries each block WRITES gives exact
// row sums with no double counting.
// R13 lesson: the mirror reduce must be register-accumulate (per-thread row
// ownership), NOT shfl-per-q (240 shfls -> +43us).
__global__ __launch_bounds__(256, 2) void gemm_sym(
    const float* __restrict__ V, const float* __restrict__ alpha_p,
    float2* __restrict__ Sbuf, float* __restrict__ rsum) {
  // LDS union: staging (As|Bs = 46080 B) then transpose buffer Ts (33792 B)
  __shared__ __align__(16) char smem_raw[2 * TN * KP * 4 + 2 * TM * KP * 4];
  float (*As)[TN][KP] = reinterpret_cast<float (*)[TN][KP]>(smem_raw);
  float (*Bs)[TM][KP] = reinterpret_cast<float (*)[TM][KP]>(smem_raw + 2 * TN * KP * 4);
  float2 (*Ts)[TN + 1] = reinterpret_cast<float2 (*)[TN + 1]>(smem_raw);

  const int b = blockIdx.y;
  // map blockIdx.x -> (ni, mj): groups g = ni>>2 have 4*(8-g) tiles each
  int id = blockIdx.x;
  int g = 0;
  while (id >= 4 * (8 - g)) { id -= 4 * (8 - g); ++g; }
  const int ni = 4 * g + id / (8 - g);
  const int mj = g + id % (8 - g);
  const int n0 = ni * TN;
  const int m0 = mj * TM;

  const int t = threadIdx.x;
  const int tx = t & 31;   // m-slot: m = m0 + tx + 32*j
  const int ty = t >> 5;   // row group: rows n0 + ty*4 + i
  const float alpha = *alpha_p;
  const float* Vb = V + (size_t)b * 2 * NP * NCH;
  float* rs = rsum + (size_t)b * 3 * NP;

  float acc[2][4][4];
#pragma unroll
  for (int c = 0; c < 2; ++c)
#pragma unroll
    for (int i = 0; i < 4; ++i)
#pragma unroll
      for (int j = 0; j < 4; ++j) acc[c][i][j] = 0.f;

  for (int k0 = 0; k0 < NCH; k0 += KC) {
    __syncthreads();
    // stage A tile: 2*32*32 floats = 512 float4 -> 2 per thread
#pragma unroll
    for (int q = 0; q < 2; ++q) {
      int flat = q * 256 + t;
      int c = flat >> 8;
      int rem = flat & 255;
      int row = rem >> 3;
      int kg = rem & 7;
      float4 v4 = *(const float4*)(Vb + ((size_t)c * NP + n0 + row) * NCH + k0 + kg * 4);
      *(float4*)&As[c][row][kg * 4] = v4;
    }
    // stage B tile: 2*128*32 floats = 2048 float4 -> 8 per thread
#pragma unroll
    for (int q = 0; q < 8; ++q) {
      int flat = q * 256 + t;
      int c = flat >> 10;
      int rem = flat & 1023;
      int row = rem >> 3;
      int kg = rem & 7;
      float4 v4 = *(const float4*)(Vb + ((size_t)c * NP + m0 + row) * NCH + k0 + kg * 4);
      *(float4*)&Bs[c][row][kg * 4] = v4;
    }
    __syncthreads();

    for (int kg = 0; kg < KC; kg += 4) {
      float4 a4[2][4], b4[2][4];
#pragma unroll
      for (int c = 0; c < 2; ++c)
#pragma unroll
        for (int i = 0; i < 4; ++i)
          a4[c][i] = *(const float4*)&As[c][ty * 4 + i][kg];
#pragma unroll
      for (int c = 0; c < 2; ++c)
#pragma unroll
        for (int j = 0; j < 4; ++j)
          b4[c][j] = *(const float4*)&Bs[c][tx + 32 * j][kg];
#pragma unroll
      for (int c = 0; c < 2; ++c)
#pragma unroll
        for (int i = 0; i < 4; ++i)
#pragma unroll
          for (int j = 0; j < 4; ++j)
            acc[c][i][j] += dot4(a4[c][i], b4[c][j]);
    }
  }

  // ---- epilogue ----
  __syncthreads();  // staging reads done; smem may be reused as Ts
  float sm[3][4];
#pragma unroll
  for (int c = 0; c < 3; ++c)
#pragma unroll
    for (int i = 0; i < 4; ++i) sm[c][i] = 0.f;

#pragma unroll
  for (int i = 0; i < 4; ++i) {
    int n = n0 + ty * 4 + i;
    int nr = n >> 5, nc = n & 31;
    float2* rowp = Sbuf + ((size_t)b * NP + n) * NP;
#pragma unroll
    for (int j = 0; j < 4; ++j) {
      int m = m0 + tx + 32 * j;
      int dr = nr - (m >> 5);
      int dc = nc - (m & 31);
      float gss = __expf(-(float)(dr * dr + dc * dc) * 0.1953125f);  // 1/5.12 exact
      float wgt = (1.0f - gss) * alpha;
      float2 sv = make_float2(acc[0][i][j] * wgt, acc[1][i][j] * wgt);
      Ts[tx + 32 * j][ty * 4 + i] = sv;  // stage for mirror
      if (m >= n) {                      // direct (upper incl. diagonal)
        rowp[m] = sv;
        sm[0][i] += __expf(sv.x);
        sm[1][i] += __expf(sv.y);
        sm[2][i] += __expf(0.5f * (sv.x + sv.y));
      }
    }
  }
  // direct row-partials: reduce over 32 tx lanes, atomic per (c, row)
#pragma unroll
  for (int off = 1; off < 32; off <<= 1) {
#pragma unroll
    for (int c = 0; c < 3; ++c)
#pragma unroll
      for (int i = 0; i < 4; ++i)
        sm[c][i] += __shfl_xor(sm[c][i], off, 64);
  }
  if (tx == 0) {
#pragma unroll
    for (int c = 0; c < 3; ++c)
#pragma unroll
      for (int i = 0; i < 4; ++i)
        atomicAdd(&rs[(size_t)c * NP + (n0 + ty * 4 + i)], sm[c][i]);
  }

  __syncthreads();
  // mirror write: Sbuf[m][n] = Ts[ml][r] for m > n; coalesced 256B bursts
#pragma unroll
  for (int q = 0; q < 16; ++q) {
    int flat = q * 256 + t;
    int ml = flat >> 5;
    int r = flat & 31;
    int m = m0 + ml;
    int n = n0 + r;
    if (m > n) Sbuf[((size_t)b * NP + m) * NP + n] = Ts[ml][r];
  }
  // mirror row-partials: thread owns row ml = t>>1, half the r range;
  // register accumulation (NO per-q shfl), one partner-merge, 3 atomics/row.
  {
    int ml = t >> 1;
    int rh = (t & 1) * 16;
    int m = m0 + ml;
    float e0 = 0.f, e1 = 0.f, e2 = 0.f;
#pragma unroll
    for (int rr = 0; rr < 16; ++rr) {
      int r = rh + rr;
      int n = n0 + r;
      float2 sv = Ts[ml][r];
      if (m > n) {
        e0 += __expf(sv.x);
        e1 += __expf(sv.y);
        e2 += __expf(0.5f * (sv.x + sv.y));
      }
    }
    e0 += __shfl_xor(e0, 1, 64);
    e1 += __shfl_xor(e1, 1, 64);
    e2 += __shfl_xor(e2, 1, 64);
    if ((t & 1) == 0) {
      atomicAdd(&rs[(size_t)0 * NP + m], e0);
      atomicAdd(&rs[(size_t)1 * NP + m], e1);
      atomicAdd(&rs[(size_t)2 * NP + m], e2);
    }
  }
}

// reciprocal in-place: rinv[i] = 1/rsum[i]
__global__ __launch_bounds__(256) void recip_kernel(float* __restrict__ p, int nelem) {
  int i = blockIdx.x * 256 + threadIdx.x;
  if (i < nelem) p[i] = 1.0f / p[i];
}

// topk: one block per (b, n-row): A=exp(2s)*rinv_n*rinv_m, top-3, scatter.
__global__ __launch_bounds__(256, 4) void topk_kernel(
    const float2* __restrict__ Sbuf, const float* __restrict__ rinv,
    float* __restrict__ out) {
  const int n = blockIdx.x, b = blockIdx.y;
  const int t = threadIdx.x;
  const float* rb = rinv + (size_t)b * 3 * NP;
  float rin[3];
#pragma unroll
  for (int c = 0; c < 3; ++c) rin[c] = rb[c * NP + n];
  const float2* row = Sbuf + ((size_t)b * NP + n) * NP;

  float t0[3] = {0.f, 0.f, 0.f}, t1[3] = {0.f, 0.f, 0.f}, t2[3] = {0.f, 0.f, 0.f};
#pragma unroll
  for (int q = 0; q < 4; ++q) {
    int m = t + q * 256;
    float2 s01 = row[m];
    float s[3];
    s[0] = s01.x; s[1] = s01.y; s[2] = 0.5f * (s01.x + s01.y);
#pragma unroll
    for (int c = 0; c < 3; ++c) {
      float a = __expf(2.0f * s[c]) * rin[c] * rb[c * NP + m];
      top3_ins(t0[c], t1[c], t2[c], a);
    }
  }
#pragma unroll
  for (int off = 1; off < 64; off <<= 1) {
#pragma unroll
    for (int c = 0; c < 3; ++c) {
      float o0 = __shfl_xor(t0[c], off, 64);
      float o1 = __shfl_xor(t1[c], off, 64);
      float o2 = __shfl_xor(t2[c], off, 64);
      top3_ins(t0[c], t1[c], t2[c], o0);
      top3_ins(t0[c], t1[c], t2[c], o1);
      top3_ins(t0[c], t1[c], t2[c], o2);
    }
  }
  __shared__ float lds[4][9];
  if ((t & 63) == 0) {
    int w = t >> 6;
#pragma unroll
    for (int c = 0; c < 3; ++c) {
      lds[w][c * 3 + 0] = t0[c];
      lds[w][c * 3 + 1] = t1[c];
      lds[w][c * 3 + 2] = t2[c];
    }
  }
  __syncthreads();
  if (t == 0) {
#pragma unroll
    for (int w = 1; w < 4; ++w)
#pragma unroll
      for (int c = 0; c < 3; ++c) {
        top3_ins(t0[c], t1[c], t2[c], lds[w][c * 3 + 0]);
        top3_ins(t0[c], t1[c], t2[c], lds[w][c * 3 + 1]);
        top3_ins(t0[c], t1[c], t2[c], lds[w][c * 3 + 2]);
      }
    int pr = n >> 5, pc = n & 31;
#pragma unroll
    for (int c = 0; c < 3; ++c) {
      int ii0, jj0, ii1 = -1, jj1 = -1;
      if (c == 0)      { ii0 = 2 * pr;     jj0 = 2 * pc; }
      else if (c == 1) { ii0 = 2 * pr + 1; jj0 = 2 * pc + 1; }
      else             { ii0 = 2 * pr;     jj0 = 2 * pc + 1;
                         ii1 = 2 * pr + 1; jj1 = 2 * pc; }
      out[(((size_t)b * 3 + 0) * NH + ii0) * NW + jj0] = t0[c];
      out[(((size_t)b * 3 + 1) * NH + ii0) * NW + jj0] = t1[c];
      out[(((size_t)b * 3 + 2) * NH + ii0) * NW + jj0] = t2[c];
      if (ii1 >= 0) {
        out[(((size_t)b * 3 + 0) * NH + ii1) * NW + jj1] = t0[c];
        out[(((size_t)b * 3 + 1) * NH + ii1) * NW + jj1] = t1[c];
        out[(((size_t)b * 3 + 2) * NH + ii1) * NW + jj1] = t2[c];
      }
    }
  }
}

// ================= FALLBACK PATH (round-1 kernels, verified) =================
template <int PASS>
__global__ __launch_bounds__(256, 2) void corr_kernel(
    const float* __restrict__ V, const float* __restrict__ alpha_p,
    float* __restrict__ rsum_g, float* __restrict__ out) {
  __shared__ __align__(16) float As[2][TN][KP];
  __shared__ __align__(16) float Bs[2][TM][KP];

  const int b = blockIdx.y;
  const int n0 = blockIdx.x * TN;
  const int t = threadIdx.x;
  const int tx = t & 31;
  const int ty = t >> 5;
  const float alpha = *alpha_p;
  const float* Vb = V + (size_t)b * 2 * NP * NCH;

  float sm[3][4];
  float t0[3][4], t1[3][4], t2[3][4];
  float rin[3][4];
#pragma unroll
  for (int c = 0; c < 3; ++c)
#pragma unroll
    for (int i = 0; i < 4; ++i) {
      sm[c][i] = 0.f;
      t0[c][i] = 0.f; t1[c][i] = 0.f; t2[c][i] = 0.f;
    }
  if (PASS == 2) {
#pragma unroll
    for (int c = 0; c < 3; ++c)
#pragma unroll
      for (int i = 0; i < 4; ++i) {
        int n = n0 + ty * 4 + i;
        rin[c][i] = 1.0f / rsum_g[((size_t)b * 3 + c) * NP + n];
      }
  }

  for (int mc = 0; mc < NP / TM; ++mc) {
    const int m0 = mc * TM;
    float acc[2][4][4];
#pragma unroll
    for (int c = 0; c < 2; ++c)
#pragma unroll
      for (int i = 0; i < 4; ++i)
#pragma unroll
        for (int j = 0; j < 4; ++j) acc[c][i][j] = 0.f;

    for (int k0 = 0; k0 < NCH; k0 += KC) {
      __syncthreads();
#pragma unroll
      for (int q = 0; q < 2; ++q) {
        int flat = q * 256 + t;
        int c = flat >> 8;
        int rem = flat & 255;
        int row = rem >> 3;
        int kg = rem & 7;
        float4 v4 = *(const float4*)(Vb + ((size_t)c * NP + n0 + row) * NCH + k0 + kg * 4);
        *(float4*)&As[c][row][kg * 4] = v4;
      }
#pragma unroll
      for (int q = 0; q < 8; ++q) {
        int flat = q * 256 + t;
        int c = flat >> 10;
        int rem = flat & 1023;
        int row = rem >> 3;
        int kg = rem & 7;
        float4 v4 = *(const float4*)(Vb + ((size_t)c * NP + m0 + row) * NCH + k0 + kg * 4);
        *(float4*)&Bs[c][row][kg * 4] = v4;
      }
      __syncthreads();

      for (int kg = 0; kg < KC; kg += 4) {
        float4 a4[2][4], b4[2][4];
#pragma unroll
        for (int c = 0; c < 2; ++c)
#pragma unroll
          for (int i = 0; i < 4; ++i)
            a4[c][i] = *(const float4*)&As[c][ty * 4 + i][kg];
#pragma unroll
        for (int c = 0; c < 2; ++c)
#pragma unroll
          for (int j = 0; j < 4; ++j)
            b4[c][j] = *(const float4*)&Bs[c][tx + 32 * j][kg];
#pragma unroll
        for (int c = 0; c < 2; ++c)
#pragma unroll
          for (int i = 0; i < 4; ++i)
#pragma unroll
            for (int j = 0; j < 4; ++j)
              acc[c][i][j] += dot4(a4[c][i], b4[c][j]);
      }
    }

    float rim[3][4];
    if (PASS == 2) {
#pragma unroll
      for (int c = 0; c < 3; ++c)
#pragma unroll
        for (int j = 0; j < 4; ++j) {
          int m = m0 + tx + 32 * j;
          rim[c][j] = 1.0f / rsum_g[((size_t)b * 3 + c) * NP + m];
        }
    }
#pragma unroll
    for (int i = 0; i < 4; ++i) {
      int n = n0 + ty * 4 + i;
      int nr = n >> 5, nc = n & 31;
      float s[3][4];
#pragma unroll
      for (int j = 0; j < 4; ++j) {
        int m = m0 + tx + 32 * j;
        int dr = nr - (m >> 5);
        int dc = nc - (m & 31);
        float g = __expf(-(float)(dr * dr + dc * dc) * 0.1953125f);
        float wgt = (1.0f - g) * alpha;
        float s0v = acc[0][i][j] * wgt;
        float s1v = acc[1][i][j] * wgt;
        s[0][j] = s0v; s[1][j] = s1v; s[2][j] = 0.5f * (s0v + s1v);
      }
      if (PASS == 1) {
#pragma unroll
        for (int c = 0; c < 3; ++c) {
          sm[c][i] += __expf(s[c][0]) + __expf(s[c][1]) +
                      __expf(s[c][2]) + __expf(s[c][3]);
        }
      } else {
#pragma unroll
        for (int c = 0; c < 3; ++c) {
#pragma unroll
          for (int j = 0; j < 4; ++j) {
            float a = __expf(2.0f * s[c][j]) * rin[c][i] * rim[c][j];
            top3_ins(t0[c][i], t1[c][i], t2[c][i], a);
          }
        }
      }
    }
  }

  if (PASS == 1) {
#pragma unroll
    for (int off = 1; off < 32; off <<= 1) {
#pragma unroll
      for (int c = 0; c < 3; ++c)
#pragma unroll
        for (int i = 0; i < 4; ++i)
          sm[c][i] += __shfl_xor(sm[c][i], off, 64);
    }
    if (tx == 0) {
#pragma unroll
      for (int c = 0; c < 3; ++c)
#pragma unroll
        for (int i = 0; i < 4; ++i) {
          int n = n0 + ty * 4 + i;
          rsum_g[((size_t)b * 3 + c) * NP + n] = sm[c][i];
        }
    }
  } else {
#pragma unroll
    for (int off = 1; off < 32; off <<= 1) {
#pragma unroll
      for (int c = 0; c < 3; ++c)
#pragma unroll
        for (int i = 0; i < 4; ++i) {
          float o0 = __shfl_xor(t0[c][i], off, 64);
          float o1 = __shfl_xor(t1[c][i], off, 64);
          float o2 = __shfl_xor(t2[c][i], off, 64);
          top3_ins(t0[c][i], t1[c][i], t2[c][i], o0);
          top3_ins(t0[c][i], t1[c][i], t2[c][i], o1);
          top3_ins(t0[c][i], t1[c][i], t2[c][i], o2);
        }
    }
    if (tx == 0) {
#pragma unroll
      for (int c = 0; c < 3; ++c)
#pragma unroll
        for (int i = 0; i < 4; ++i) {
          int n = n0 + ty * 4 + i;
          int pr = n >> 5, pc = n & 31;
          float v0 = t0[c][i], v1 = t1[c][i], v2 = t2[c][i];
          int ii0, jj0, ii1 = -1, jj1 = -1;
          if (c == 0)      { ii0 = 2 * pr;     jj0 = 2 * pc; }
          else if (c == 1) { ii0 = 2 * pr + 1; jj0 = 2 * pc + 1; }
          else             { ii0 = 2 * pr;     jj0 = 2 * pc + 1;
                             ii1 = 2 * pr + 1; jj1 = 2 * pc; }
          out[(((size_t)b * 3 + 0) * NH + ii0) * NW + jj0] = v0;
          out[(((size_t)b * 3 + 1) * NH + ii0) * NW + jj0] = v1;
          out[(((size_t)b * 3 + 2) * NH + ii0) * NW + jj0] = v2;
          if (ii1 >= 0) {
            out[(((size_t)b * 3 + 0) * NH + ii1) * NW + jj1] = v0;
            out[(((size_t)b * 3 + 1) * NH + ii1) * NW + jj1] = v1;
            out[(((size_t)b * 3 + 2) * NH + ii1) * NW + jj1] = v2;
          }
        }
    }
  }
}

extern "C" void kernel_launch(void* const* d_in, const int* in_sizes, int n_in,
                              void* d_out, int out_size, void* d_ws, size_t ws_size,
                              hipStream_t stream) {
  const float* x = (const float*)d_in[0];
  const float* alpha = (const float*)d_in[1];
  float* out = (float*)d_out;

  // workspace layout (floats)
  const size_t nV = (size_t)NB * 2 * NP * NCH;      // 4,194,304
  const size_t nRs = (size_t)NB * 3 * NP;           // 49,152 (rsum -> rinv; fallback rsum)
  const size_t nS = (size_t)NB * NP * NP;           // 16,777,216 float2 slots

  float* V = (float*)d_ws;
  float* rsum = V + nV;
  float2* Sbuf = (float2*)(rsum + nRs);

  const size_t need_bytes = (nV + nRs) * 4 + nS * 8;

  if (ws_size >= need_bytes) {
    zero_kernel<<<(NB * 3 * NP + 255) / 256, 256, 0, stream>>>(rsum, NB * 3 * NP);
    prep_kernel<<<128, 256, 0, stream>>>(x, V);
    gemm_sym<<<dim3(NTILE, NB), 256, 0, stream>>>(V, alpha, Sbuf, rsum);
    recip_kernel<<<(NB * 3 * NP + 255) / 256, 256, 0, stream>>>(rsum, NB * 3 * NP);
    topk_kernel<<<dim3(NP, NB), 256, 0, stream>>>(Sbuf, rsum, out);
  } else {
    prep_kernel<<<128, 256, 0, stream>>>(x, V);
    corr_kernel<1><<<dim3(NP / TN, NB), 256, 0, stream>>>(V, alpha, rsum, out);
    corr_kernel<2><<<dim3(NP / TN, NB), 256, 0, stream>>>(V, alpha, rsum, out);
  }
}